// Round 1
// baseline (261.999 us; speedup 1.0000x reference)
//
#include <hip/hip_runtime.h>
#include <cstdint>

#define N_NODES 50000
#define N_EDGES 800000
#define F_IN    128
#define N_HEADS 4
#define HEAD_DIM 32
#define F_OUT   128
#define NBLK_SCAN 196   // ceil(50000/256)

// ---------------------------------------------------------------------------
// K1: h = x @ W  (fp32, LDS-tiled), fused alpha_l/alpha_r epilogue.
// Block = 256 threads, tile = 128 rows x 128 cols, BK = 64 (two phases).
// Thread (c=t&15, g=t>>4) computes rows 8g..8g+7, cols {4c..4c+3, 64+4c..67+4c}.
// x staged transposed (xT[k][row]) so per-k row reads are ds_read_b128.
// Within a wave k is uniform, so inner-loop LDS reads are conflict-free unpadded.
// ---------------------------------------------------------------------------
__global__ __launch_bounds__(256) void k_gemm_alpha(
    const float* __restrict__ x, const float* __restrict__ W,
    const float* __restrict__ attl, const float* __restrict__ attr,
    float* __restrict__ h, float* __restrict__ aL, float* __restrict__ aR)
{
    __shared__ float Wl[64 * 128];   // Wl[kk][col]
    __shared__ float xT[64 * 128];   // xT[kk][row]
    const int t = threadIdx.x;
    const int row0 = blockIdx.x * 128;

    const int c = t & 15;
    const int g = t >> 4;

    float4 acc0[8], acc1[8];
#pragma unroll
    for (int r = 0; r < 8; ++r) {
        acc0[r] = make_float4(0.f, 0.f, 0.f, 0.f);
        acc1[r] = make_float4(0.f, 0.f, 0.f, 0.f);
    }

    const int wc4  = t & 31;            // W stage: f4 col index
    const int wkk0 = t >> 5;            // W stage: k row base
    const int xr8  = t & 7;             // x stage
    const int xc16 = (t >> 3) & 15;     // f4 index within 64-k chunk
    const int xrh  = t >> 7;            // 0/1

    for (int kt = 0; kt < 128; kt += 64) {
        if (kt) __syncthreads();
        // stage W chunk
#pragma unroll
        for (int i = 0; i < 8; ++i) {
            int kk = wkk0 + 8 * i;
            float4 w = *(const float4*)&W[(kt + kk) * F_OUT + 4 * wc4];
            *(float4*)&Wl[kk * 128 + 4 * wc4] = w;
        }
        // stage x chunk, transposed
#pragma unroll
        for (int i = 0; i < 8; ++i) {
            int r = xr8 + 8 * xrh + 16 * i;
            int grow = row0 + r;
            float4 v = make_float4(0.f, 0.f, 0.f, 0.f);
            if (grow < N_NODES) v = *(const float4*)&x[grow * F_IN + kt + 4 * xc16];
            xT[(4 * xc16 + 0) * 128 + r] = v.x;
            xT[(4 * xc16 + 1) * 128 + r] = v.y;
            xT[(4 * xc16 + 2) * 128 + r] = v.z;
            xT[(4 * xc16 + 3) * 128 + r] = v.w;
        }
        __syncthreads();

#pragma unroll 4
        for (int k = 0; k < 64; ++k) {
            float4 xa = *(float4*)&xT[k * 128 + 8 * g];
            float4 xb = *(float4*)&xT[k * 128 + 8 * g + 4];
            float4 wa = *(float4*)&Wl[k * 128 + 4 * c];
            float4 wb = *(float4*)&Wl[k * 128 + 64 + 4 * c];
            float xr[8] = {xa.x, xa.y, xa.z, xa.w, xb.x, xb.y, xb.z, xb.w};
#pragma unroll
            for (int r = 0; r < 8; ++r) {
                acc0[r].x = fmaf(xr[r], wa.x, acc0[r].x);
                acc0[r].y = fmaf(xr[r], wa.y, acc0[r].y);
                acc0[r].z = fmaf(xr[r], wa.z, acc0[r].z);
                acc0[r].w = fmaf(xr[r], wa.w, acc0[r].w);
                acc1[r].x = fmaf(xr[r], wb.x, acc1[r].x);
                acc1[r].y = fmaf(xr[r], wb.y, acc1[r].y);
                acc1[r].z = fmaf(xr[r], wb.z, acc1[r].z);
                acc1[r].w = fmaf(xr[r], wb.w, acc1[r].w);
            }
        }
    }

    // epilogue: write h tile; reduce alpha_l / alpha_r per (row, head)
    const int h0 = c >> 3;        // head of acc0 cols (0 or 1)
    const int h1 = 2 + (c >> 3);  // head of acc1 cols (2 or 3)
    const int d0 = (c & 7) * 4;   // dim offset within head
    const float4 al0 = *(const float4*)&attl[h0 * HEAD_DIM + d0];
    const float4 al1 = *(const float4*)&attl[h1 * HEAD_DIM + d0];
    const float4 ar0 = *(const float4*)&attr[h0 * HEAD_DIM + d0];
    const float4 ar1 = *(const float4*)&attr[h1 * HEAD_DIM + d0];

#pragma unroll
    for (int r = 0; r < 8; ++r) {
        int row = row0 + 8 * g + r;
        float pl0 = acc0[r].x * al0.x + acc0[r].y * al0.y + acc0[r].z * al0.z + acc0[r].w * al0.w;
        float pr0 = acc0[r].x * ar0.x + acc0[r].y * ar0.y + acc0[r].z * ar0.z + acc0[r].w * ar0.w;
        float pl1 = acc1[r].x * al1.x + acc1[r].y * al1.y + acc1[r].z * al1.z + acc1[r].w * al1.w;
        float pr1 = acc1[r].x * ar1.x + acc1[r].y * ar1.y + acc1[r].z * ar1.z + acc1[r].w * ar1.w;
#pragma unroll
        for (int d = 1; d < 8; d <<= 1) {
            pl0 += __shfl_xor(pl0, d);
            pr0 += __shfl_xor(pr0, d);
            pl1 += __shfl_xor(pl1, d);
            pr1 += __shfl_xor(pr1, d);
        }
        if (row < N_NODES) {
            *(float4*)&h[row * F_OUT + 4 * c]       = acc0[r];
            *(float4*)&h[row * F_OUT + 64 + 4 * c]  = acc1[r];
            if ((c & 7) == 0) {
                aL[row * N_HEADS + h0] = pl0;
                aL[row * N_HEADS + h1] = pl1;
                aR[row * N_HEADS + h0] = pr0;
                aR[row * N_HEADS + h1] = pr1;
            }
        }
    }
}

// ---------------------------------------------------------------------------
// K2: in-degree histogram
// ---------------------------------------------------------------------------
__global__ __launch_bounds__(256) void k_count(const int* __restrict__ ei, int* __restrict__ count)
{
    int e = blockIdx.x * 256 + threadIdx.x;
    if (e < N_EDGES) atomicAdd(&count[ei[N_EDGES + e]], 1);
}

// ---------------------------------------------------------------------------
// 2-level exclusive scan over 50000 counts (196 blocks of 256)
// ---------------------------------------------------------------------------
__device__ __forceinline__ int block_scan_excl_256(int v, int* p_total)
{
    const int t = threadIdx.x, lane = t & 63, wv = t >> 6;
    int incl = v;
#pragma unroll
    for (int d = 1; d < 64; d <<= 1) {
        int u = __shfl_up(incl, d);
        if (lane >= d) incl += u;
    }
    __shared__ int wsum[4];
    if (lane == 63) wsum[wv] = incl;
    __syncthreads();
    int woff = 0;
#pragma unroll
    for (int j = 0; j < 4; ++j) {
        int s = wsum[j];
        if (j < wv) woff += s;
    }
    if (p_total) *p_total = wsum[0] + wsum[1] + wsum[2] + wsum[3];
    __syncthreads();
    return woff + incl - v;
}

__global__ __launch_bounds__(256) void k_scan1(const int* __restrict__ count,
                                               int* __restrict__ scanned,
                                               int* __restrict__ blocksum)
{
    int i = blockIdx.x * 256 + threadIdx.x;
    int v = (i < N_NODES) ? count[i] : 0;
    int tot;
    int ex = block_scan_excl_256(v, &tot);
    if (i < N_NODES) scanned[i] = ex;
    if (threadIdx.x == 0) blocksum[blockIdx.x] = tot;
}

__global__ __launch_bounds__(256) void k_scan2(const int* __restrict__ blocksum,
                                               int* __restrict__ blockoff)
{
    int t = threadIdx.x;
    int v = (t < NBLK_SCAN) ? blocksum[t] : 0;
    int ex = block_scan_excl_256(v, nullptr);
    if (t < NBLK_SCAN) blockoff[t] = ex;
}

__global__ __launch_bounds__(256) void k_scan3(const int* __restrict__ scanned,
                                               const int* __restrict__ blockoff,
                                               int* __restrict__ offsets,
                                               int* __restrict__ cursor)
{
    int i = blockIdx.x * 256 + threadIdx.x;
    if (i < N_NODES) {
        int off = scanned[i] + blockoff[blockIdx.x];
        offsets[i] = off;
        cursor[i]  = off;
    }
}

// ---------------------------------------------------------------------------
// K4: per-edge attention logits -> exp, scatter CSR records (from, ex[4])
// Softmax shift by global max cancels in ex/sum(ex); after leaky_relu(0.2)
// att <= ~10 so exp() cannot overflow fp32.
// ---------------------------------------------------------------------------
__global__ __launch_bounds__(256) void k_scatter(const int* __restrict__ ei,
    const float* __restrict__ aL, const float* __restrict__ aR,
    int* __restrict__ cursor, int* __restrict__ rec_from, float4* __restrict__ rec_ex)
{
    int e = blockIdx.x * 256 + threadIdx.x;
    if (e >= N_EDGES) return;
    int from = ei[e], to = ei[N_EDGES + e];
    const float4 l = *(const float4*)&aL[from * 4];
    const float4 r = *(const float4*)&aR[to * 4];
    float a0 = l.x + r.x, a1 = l.y + r.y, a2 = l.z + r.z, a3 = l.w + r.w;
    a0 = (a0 > 0.f) ? a0 : 0.2f * a0;
    a1 = (a1 > 0.f) ? a1 : 0.2f * a1;
    a2 = (a2 > 0.f) ? a2 : 0.2f * a2;
    a3 = (a3 > 0.f) ? a3 : 0.2f * a3;
    float4 ex = make_float4(__expf(a0), __expf(a1), __expf(a2), __expf(a3));
    int pos = atomicAdd(&cursor[to], 1);
    rec_from[pos] = from;
    rec_ex[pos]   = ex;
}

// ---------------------------------------------------------------------------
// K5: pull aggregation. One wave per node; lane owns 2 output dims.
// out[n] = (sum_e ex_e * h[from_e]) / (sum_e ex_e + 1e-9) + bias
// ---------------------------------------------------------------------------
__global__ __launch_bounds__(256) void k_agg(const int* __restrict__ rec_from,
    const float* __restrict__ rec_ex, const int* __restrict__ count,
    const int* __restrict__ offsets, const float* __restrict__ h,
    const float* __restrict__ bias, float* __restrict__ out)
{
    const int lane = threadIdx.x & 63;
    const int n = blockIdx.x * 4 + (threadIdx.x >> 6);
    if (n >= N_NODES) return;
    const int cnt = count[n];
    const int off = offsets[n];
    const int head = lane >> 4;   // (2*lane)/32
    float ax = 0.f, ay = 0.f, ds = 0.f;
    for (int base = 0; base < cnt; base += 64) {
        const int m = min(64, cnt - base);
        int vf = 0;
        if (lane < m) vf = rec_from[off + base + lane];   // coalesced preload
        for (int i = 0; i < m; ++i) {
            const int fi = __shfl(vf, i);
            const float eh = rec_ex[(off + base + i) * 4 + head];
            const float2 h2 = *(const float2*)&h[fi * F_OUT + 2 * lane];
            ax = fmaf(eh, h2.x, ax);
            ay = fmaf(eh, h2.y, ay);
            ds += eh;
        }
    }
    const float inv = 1.0f / (ds + 1e-9f);
    const float2 b2 = *(const float2*)&bias[2 * lane];
    float2 o;
    o.x = ax * inv + b2.x;
    o.y = ay * inv + b2.y;
    *(float2*)&out[n * F_OUT + 2 * lane] = o;
}

// ---------------------------------------------------------------------------
extern "C" void kernel_launch(void* const* d_in, const int* in_sizes, int n_in,
                              void* d_out, int out_size, void* d_ws, size_t ws_size,
                              hipStream_t stream)
{
    const float* x    = (const float*)d_in[0];
    const int*   ei   = (const int*)d_in[1];
    const float* W    = (const float*)d_in[2];
    const float* attl = (const float*)d_in[3];
    const float* attr = (const float*)d_in[4];
    const float* bias = (const float*)d_in[5];
    float* out = (float*)d_out;

    char* p = (char*)d_ws;
    auto carve = [&](size_t bytes) -> char* {
        char* q = p;
        p += (bytes + 255) & ~size_t(255);
        return q;
    };
    float*  h        = (float*)carve((size_t)N_NODES * F_OUT * 4);   // 25.6 MB
    float*  aL       = (float*)carve((size_t)N_NODES * 4 * 4);
    float*  aR       = (float*)carve((size_t)N_NODES * 4 * 4);
    int*    count    = (int*)carve((size_t)N_NODES * 4);
    int*    scanned  = (int*)carve((size_t)N_NODES * 4);
    int*    offsets  = (int*)carve((size_t)N_NODES * 4);
    int*    cursor   = (int*)carve((size_t)N_NODES * 4);
    int*    blocksum = (int*)carve(256 * 4);
    int*    blockoff = (int*)carve(256 * 4);
    int*    rec_from = (int*)carve((size_t)N_EDGES * 4);             // 3.2 MB
    float4* rec_ex   = (float4*)carve((size_t)N_EDGES * 16);         // 12.8 MB

    hipMemsetAsync(count, 0, N_NODES * 4, stream);

    k_gemm_alpha<<<(N_NODES + 127) / 128, 256, 0, stream>>>(x, W, attl, attr, h, aL, aR);
    k_count<<<(N_EDGES + 255) / 256, 256, 0, stream>>>(ei, count);
    k_scan1<<<NBLK_SCAN, 256, 0, stream>>>(count, scanned, blocksum);
    k_scan2<<<1, 256, 0, stream>>>(blocksum, blockoff);
    k_scan3<<<NBLK_SCAN, 256, 0, stream>>>(scanned, blockoff, offsets, cursor);
    k_scatter<<<(N_EDGES + 255) / 256, 256, 0, stream>>>(ei, aL, aR, cursor, rec_from, rec_ex);
    k_agg<<<(N_NODES + 3) / 4, 256, 0, stream>>>(rec_from, (const float*)rec_ex, count, offsets, h, bias, out);
}